// Round 13
// baseline (151.406 us; speedup 1.0000x reference)
//
#include <hip/hip_runtime.h>
#include <hip/hip_bf16.h>
#include <stdint.h>

typedef __attribute__((ext_vector_type(8))) short short8;
typedef __attribute__((ext_vector_type(4))) float f32x4;
typedef unsigned short u16;

#define AS1 __attribute__((address_space(1)))
#define AS3 __attribute__((address_space(3)))

__device__ __forceinline__ u16 f2b(float f) {
  union { float f; uint32_t u; } c; c.f = f;
  uint32_t u = c.u;
  return (u16)((u + 0x7fffu + ((u >> 16) & 1u)) >> 16);  // RNE
}
__device__ __forceinline__ float b2f(u16 b) {
  union { uint32_t u; float f; } c; c.u = ((uint32_t)b) << 16;
  return c.f;
}

// ---------------- conversion kernels (verified round 1) ----------------
__global__ void cvt_bf16_kernel(const float* __restrict__ src,
                                u16* __restrict__ dst, int n4) {
  int i = blockIdx.x * blockDim.x + threadIdx.x;
  if (i >= n4) return;
  const float4 v = reinterpret_cast<const float4*>(src)[i];
  ushort4 o;
  o.x = f2b(v.x); o.y = f2b(v.y); o.z = f2b(v.z); o.w = f2b(v.w);
  reinterpret_cast<ushort4*>(dst)[i] = o;
}

__global__ void cvt_transpose_kernel(const float* __restrict__ w0,
                                     const float* __restrict__ w1,
                                     const float* __restrict__ w2,
                                     u16* __restrict__ d0,
                                     u16* __restrict__ d1,
                                     u16* __restrict__ d2,
                                     int K, int N) {
  const float* src = (blockIdx.y == 0) ? w0 : (blockIdx.y == 1 ? w1 : w2);
  u16* dst = (blockIdx.y == 0) ? d0 : (blockIdx.y == 1 ? d1 : d2);
  int idx = blockIdx.x * blockDim.x + threadIdx.x;
  if (idx >= K * N) return;
  int k = idx / N, n = idx - k * N;
  dst[(size_t)n * K + k] = f2b(src[idx]);
}

// ---- r10 frame + B-direct-from-L2: A-only LDS staging, b in registers ----
// IDENTICAL to round 12 except the staging LDS destination now includes the
// per-wave offset (+ wid*1024 bytes).  r12's bug: global_load_lds dest is
// wave-uniform + lane*16; without the wid term all 4 waves wrote the same
// 1KB and 3/4 of the A tile was never staged (absmax 4.12).  r10's verified
// staging had wid*512 u16 == wid*1024 B; restored here.
// Frame: C[16384,N] = A[.,1024] @ Wt[N][1024]^T.  BM=BN=128, BK=64, NT=16.
// 256 thr = 4 waves 2Mx2N, per-wave 64x64.  LDS: A-only dbuf 2x16KB.
// B (weights, L2-hot) loaded straight to regs one tile ahead, ping-pong
// bE/bO.  Phases per tile t:
//  P0: RD aHI(t); GLB b01(t+1); STG_A01(t+1); BAR; LG(4); MFMA aLO.bc01
//  P1: GLB b23(t+1); STG_A23(t+1); BAR; LG(0); MFMA aLO.bc23
//  P2: BAR; MFMA aHI.bc23
//  P3: VMW(0); BAR; RD aLO(t+1); MFMA aHI.bc01
// Hazards (derived r12, unchanged): A-dbuf WAR >=2 barriers; RAW via
// VMW(0)+BAR; reg WAR safe by in-order issue.  Swizzle r10-verified.

#define BAR() __builtin_amdgcn_s_barrier()
#define SB() __builtin_amdgcn_sched_barrier(0)
#define LG(n) do { asm volatile("s_waitcnt lgkmcnt(" #n ")" ::: "memory"); __builtin_amdgcn_sched_barrier(0); } while (0)
#define VMW(n) do { asm volatile("s_waitcnt vmcnt(" #n ")" ::: "memory"); __builtin_amdgcn_sched_barrier(0); } while (0)

#define GEMM_PROLOG(NBN, CPX)                                              \
  constexpr int NT = 16;                                                   \
  __shared__ u16 lds[2 * 8192];                                            \
  const char* ldsb = (const char*)lds;                                     \
  const int tid = threadIdx.x, lane = tid & 63, wid = tid >> 6;            \
  const int wm = wid >> 1, wn = wid & 1;                                   \
  const int wg = ((int)blockIdx.x & 7) * (CPX) + ((int)blockIdx.x >> 3);   \
  const int bn = wg & ((NBN) - 1), bm = wg / (NBN);                        \
  const int srow = tid >> 3;                                               \
  const int swzb = ((tid & 7) ^ (srow & 7)) << 4;                          \
  const int rsel = lane & 15, kg = lane >> 4;                              \
  const int sl0 = (kg ^ (rsel & 7)) << 4;                                  \
  const int sl1 = ((4 + kg) ^ (rsel & 7)) << 4;                            \
  const int aoff = (wm * 64 + rsel) * 128;                                 \
  const char* wtl = (const char*)wt +                                      \
      (size_t)(bn * 128 + wn * 64 + rsel) * 2048 + kg * 16;

#define DEF_STG_A(SRC_LO, SRC_HI)                                          \
  auto STG_A01 = [&](int t) {                                              \
    if (t >= NT) return;                                                   \
    char* dst = (char*)lds + (t & 1) * 16384 + wid * 1024;  /* r13 fix */  \
    const char* base = (t < 8) ? ((const char*)(SRC_LO) + (size_t)t * 128) \
                               : ((const char*)(SRC_HI) + (size_t)(t - 8) * 128); \
    _Pragma("unroll")                                                      \
    for (int i = 0; i < 2; ++i) {                                          \
      const char* s = base + (size_t)(bm * 128 + i * 32 + srow) * 1024 + swzb; \
      __builtin_amdgcn_global_load_lds((const AS1 void*)s,                 \
                                       (AS3 void*)(dst + i * 4096), 16, 0, 0); \
    }                                                                      \
  };                                                                       \
  auto STG_A23 = [&](int t) {                                              \
    if (t >= NT) return;                                                   \
    char* dst = (char*)lds + (t & 1) * 16384 + wid * 1024;  /* r13 fix */  \
    const char* base = (t < 8) ? ((const char*)(SRC_LO) + (size_t)t * 128) \
                               : ((const char*)(SRC_HI) + (size_t)(t - 8) * 128); \
    _Pragma("unroll")                                                      \
    for (int i = 2; i < 4; ++i) {                                          \
      const char* s = base + (size_t)(bm * 128 + i * 32 + srow) * 1024 + swzb; \
      __builtin_amdgcn_global_load_lds((const AS1 void*)s,                 \
                                       (AS3 void*)(dst + i * 4096), 16, 0, 0); \
    }                                                                      \
  };

#define DEF_HELPERS                                                        \
  auto RD_ALO = [&](int t) {                                               \
    const char* p = ldsb + (t & 1) * 16384 + aoff;                         \
    _Pragma("unroll")                                                      \
    for (int mi = 0; mi < 2; ++mi) {                                       \
      aLO[mi][0] = *(const short8*)(p + mi * 2048 + sl0);                  \
      aLO[mi][1] = *(const short8*)(p + mi * 2048 + sl1);                  \
    }                                                                      \
  };                                                                       \
  auto RD_AHI = [&](int t) {                                               \
    const char* p = ldsb + (t & 1) * 16384 + aoff;                         \
    _Pragma("unroll")                                                      \
    for (int mi = 0; mi < 2; ++mi) {                                       \
      aHI[mi][0] = *(const short8*)(p + (2 + mi) * 2048 + sl0);            \
      aHI[mi][1] = *(const short8*)(p + (2 + mi) * 2048 + sl1);            \
    }                                                                      \
  };                                                                       \
  auto LDB01 = [&](auto& d, int t) {                                       \
    if (t >= NT) return;                                                   \
    const char* p = wtl + (size_t)t * 128;                                 \
    _Pragma("unroll")                                                      \
    for (int nf = 0; nf < 2; ++nf) {                                       \
      d[nf][0] = *(const short8*)(p + nf * 32768);                         \
      d[nf][1] = *(const short8*)(p + nf * 32768 + 64);                    \
    }                                                                      \
  };                                                                       \
  auto LDB23 = [&](auto& d, int t) {                                       \
    if (t >= NT) return;                                                   \
    const char* p = wtl + (size_t)t * 128;                                 \
    _Pragma("unroll")                                                      \
    for (int nf = 2; nf < 4; ++nf) {                                       \
      d[nf][0] = *(const short8*)(p + nf * 32768);                         \
      d[nf][1] = *(const short8*)(p + nf * 32768 + 64);                    \
    }                                                                      \
  };                                                                       \
  auto MM = [&](auto& A, auto& Bv, int mb, int nb) {                       \
    __builtin_amdgcn_s_setprio(1);                                         \
    _Pragma("unroll")                                                      \
    for (int ks = 0; ks < 2; ++ks)                                         \
      _Pragma("unroll")                                                    \
      for (int mi = 0; mi < 2; ++mi)                                       \
        _Pragma("unroll")                                                  \
        for (int ni = 0; ni < 2; ++ni)                                     \
          acc[mb + mi][nb + ni] = __builtin_amdgcn_mfma_f32_16x16x32_bf16( \
              A[mi][ks], Bv[nb + ni][ks], acc[mb + mi][nb + ni], 0, 0, 0); \
    __builtin_amdgcn_s_setprio(0);                                         \
  };

#define TILE(t, bc, bnx)                                                   \
  do {                                                                     \
    RD_AHI(t); LDB01(bnx, (t) + 1); STG_A01((t) + 1);                      \
    BAR(); LG(4); MM(aLO, bc, 0, 0);                                       \
    LDB23(bnx, (t) + 1); STG_A23((t) + 1);                                 \
    BAR(); LG(0); MM(aLO, bc, 0, 2);                                       \
    BAR(); MM(aHI, bc, 2, 2);                                              \
    VMW(0); BAR();                                                         \
    if ((t) + 1 < NT) RD_ALO((t) + 1);                                     \
    SB(); MM(aHI, bc, 2, 0);                                               \
  } while (0)

// ---------------- GATES: C[16384,1024] = [x|h] @ [Wz^T;Wr^T]^T ----------
__global__ __launch_bounds__(256, 2) void gates_k(
    const u16* __restrict__ xb, const u16* __restrict__ hb,
    const u16* __restrict__ wt,
    u16* __restrict__ o_z, u16* __restrict__ o_rh) {
  GEMM_PROLOG(8, 128)                       // grid 1024 = 128bm x 8bn
  DEF_STG_A(xb, hb)
  f32x4 acc[4][4] = {};
  short8 aLO[2][2], aHI[2][2], bE[4][2], bO[4][2];
  DEF_HELPERS

  // prologue
  STG_A01(0); STG_A23(0); LDB01(bE, 0); LDB23(bE, 0);
  VMW(0); BAR();
  RD_ALO(0); SB();

#pragma unroll 1
  for (int j = 0; j < 8; ++j) {
    TILE(2 * j, bE, bO);
    TILE(2 * j + 1, bO, bE);
  }

  // epilogue (r10-verified layout/numerics)
  const int row0 = bm * 128 + wm * 64 + kg * 4;
  const int col0 = bn * 128 + wn * 64 + rsel;
  if (bn < 4) {  // z half (global cols 0..511)
#pragma unroll
    for (int mf = 0; mf < 4; ++mf)
#pragma unroll
      for (int nf = 0; nf < 4; ++nf)
#pragma unroll
        for (int q = 0; q < 4; ++q) {
          const int row = row0 + mf * 16 + q;
          const int col = col0 + nf * 16;
          const float zf = 1.f / (1.f + __expf(-acc[mf][nf][q]));
          o_z[(size_t)row * 512 + col] = f2b(zf);
        }
  } else {       // r half (global cols 512..1023)
#pragma unroll
    for (int mf = 0; mf < 4; ++mf)
#pragma unroll
      for (int nf = 0; nf < 4; ++nf)
#pragma unroll
        for (int q = 0; q < 4; ++q) {
          const int row = row0 + mf * 16 + q;
          const int col = col0 + nf * 16 - 512;
          const size_t idx = (size_t)row * 512 + col;
          const float rf = 1.f / (1.f + __expf(-acc[mf][nf][q]));
          o_rh[idx] = f2b(rf * b2f(hb[idx]));
        }
  }
}

// ---------------- CAND: C[16384,512] = [x|rh] @ Wh^T; fused output ------
__global__ __launch_bounds__(256, 2) void cand_k(
    const u16* __restrict__ xb, const u16* __restrict__ rhb,
    const u16* __restrict__ wt, const u16* __restrict__ hb,
    const u16* __restrict__ zb_in, float* __restrict__ o_f) {
  GEMM_PROLOG(4, 64)                        // grid 512 = 128bm x 4bn
  DEF_STG_A(xb, rhb)
  f32x4 acc[4][4] = {};
  short8 aLO[2][2], aHI[2][2], bE[4][2], bO[4][2];
  DEF_HELPERS

  STG_A01(0); STG_A23(0); LDB01(bE, 0); LDB23(bE, 0);
  VMW(0); BAR();
  RD_ALO(0); SB();

#pragma unroll 1
  for (int j = 0; j < 8; ++j) {
    TILE(2 * j, bE, bO);
    TILE(2 * j + 1, bO, bE);
  }

  // epilogue (r10-verified): out = z*h + (1-z)*tanh(s)
  const int row0 = bm * 128 + wm * 64 + kg * 4;
  const int col0 = bn * 128 + wn * 64 + rsel;
#pragma unroll
  for (int mf = 0; mf < 4; ++mf)
#pragma unroll
    for (int nf = 0; nf < 4; ++nf)
#pragma unroll
      for (int q = 0; q < 4; ++q) {
        const int row = row0 + mf * 16 + q;
        const int col = col0 + nf * 16;
        const size_t idx = (size_t)row * 512 + col;
        const float s = acc[mf][nf][q];
        const float hh = 2.f / (1.f + __expf(-2.f * s)) - 1.f;  // tanh
        const float z = b2f(zb_in[idx]);
        o_f[idx] = z * b2f(hb[idx]) + (1.f - z) * hh;
      }
}

// ---------------- launch ----------------
extern "C" void kernel_launch(void* const* d_in, const int* in_sizes, int n_in,
                              void* d_out, int out_size, void* d_ws, size_t ws_size,
                              hipStream_t stream) {
  const float* inputs = (const float*)d_in[0];
  const float* h_prev = (const float*)d_in[1];
  const float* Wz = (const float*)d_in[2];
  const float* Wr = (const float*)d_in[3];
  const float* Wh = (const float*)d_in[4];
  float* out = (float*)d_out;

  const int B = 16384, D = 512, U = 512, K = 1024;

  u16* xb = (u16*)d_ws;                 // [B,D] bf16
  u16* hb = xb + (size_t)B * D;         // [B,U] bf16
  u16* wzt = hb + (size_t)B * U;        // [1024,1024]: rows 0-511 Wz^T, 512-1023 Wr^T
  u16* wrt = wzt + (size_t)K * U;
  u16* wht = wrt + (size_t)K * U;       // [512,1024] Wh^T
  u16* zb = wht + (size_t)K * U;        // [B,U] bf16
  u16* rhb = zb + (size_t)B * U;        // [B,U] bf16

  const int n4 = (B * D) / 4;
  cvt_bf16_kernel<<<(n4 + 255) / 256, 256, 0, stream>>>(inputs, xb, n4);
  cvt_bf16_kernel<<<(n4 + 255) / 256, 256, 0, stream>>>(h_prev, hb, n4);
  dim3 tg((K * U + 255) / 256, 3);
  cvt_transpose_kernel<<<tg, 256, 0, stream>>>(Wz, Wr, Wh, wzt, wrt, wht, K, U);

  // gates: 128bm x 8bn = 1024 blocks (2/CU)
  gates_k<<<dim3(1024), 256, 0, stream>>>(xb, hb, wzt, zb, rhb);
  // candidate: 128bm x 4bn = 512 blocks (2/CU)
  cand_k<<<dim3(512), 256, 0, stream>>>(xb, rhb, wht, hb, zb, out);
}